// Round 2
// baseline (80.969 us; speedup 1.0000x reference)
//
#include <hip/hip_runtime.h>
#include <math.h>

// TWO waves per sample, ONE sample per block (block=128). Amplitude i:
//   bits 0..5 -> lane, bits 6..8 -> register (8 float2/lane), bit 9 -> wave.
// Layers: fused U_q = RX(theta)*RY(enc); CNOT chain = permutation
// src(j) = j ^ ((j&511)<<1). Layer-0 acts on |0..0> -> product state.
// Layer-2's FINAL CNOT chain is absorbed into the head weights via
// prefix-XOR signs (W'(k) = sum_q w_q * (1-2*(k_0^..^k_q))).
//
// r8: VERIFIED r6 STRUCTURE RESTORED (r7's fused layer-0 failed absmax).
// Only bit-exact change kept: per-lane gate quadruple (gAr,gAi,gBr,gBi)
// precomputed ONCE before broadcast; every GATE_PARAMS site is now 4
// readlanes with no muls (rdlane(cT*cE,g) == rdlane(cT,g)*rdlane(cE,g),
// negation exact) -> ~120 fewer v_mul, IEEE-identical output to baseline.
// Dual purpose: (i) issue-bound win per r4/r5 evidence; (ii) a FAIL here
// would prove the handed-down baseline itself is broken, since this is
// bit-exact w.r.t. it.

#define PI_F 3.14159265358979323846f

typedef unsigned v2u __attribute__((ext_vector_type(2)));

#if defined(__has_builtin)
#if __has_builtin(__builtin_amdgcn_permlane16_swap)
#define HAVE_PL16 1
#endif
#if __has_builtin(__builtin_amdgcn_permlane32_swap)
#define HAVE_PL32 1
#endif
#endif

__device__ __forceinline__ float rdlane(float v, int l) {
    return __int_as_float(__builtin_amdgcn_readlane(__float_as_int(v), l));
}

// ---- VALU-pipe lane^mask partner fetch (verified r4-r6, absmax 0) ----
__device__ __forceinline__ float xor1p(float v) {
    return __int_as_float(__builtin_amdgcn_update_dpp(
        0, __float_as_int(v), 0xB1, 0xF, 0xF, true));
}
__device__ __forceinline__ float xor2p(float v) {
    return __int_as_float(__builtin_amdgcn_update_dpp(
        0, __float_as_int(v), 0x4E, 0xF, 0xF, true));
}
__device__ __forceinline__ float xor4p(float v) {   // xor7 ∘ xor3 = xor4
    int t = __builtin_amdgcn_update_dpp(0, __float_as_int(v), 0x1B, 0xF, 0xF, true);
    t = __builtin_amdgcn_update_dpp(0, t, 0x141, 0xF, 0xF, true);
    return __int_as_float(t);
}
__device__ __forceinline__ float xor8p(float v) {   // row_ror:8
    return __int_as_float(__builtin_amdgcn_update_dpp(
        0, __float_as_int(v), 0x128, 0xF, 0xF, true));
}
__device__ __forceinline__ float xor16p(float v, bool hi) {
#ifdef HAVE_PL16
    v2u r = __builtin_amdgcn_permlane16_swap(
        (unsigned)__float_as_int(v), (unsigned)__float_as_int(v), false, false);
    return __int_as_float((int)(hi ? r.x : r.y));
#else
    return __shfl_xor(v, 16);
#endif
}
__device__ __forceinline__ float xor32p(float v, bool hi) {
#ifdef HAVE_PL32
    v2u r = __builtin_amdgcn_permlane32_swap(
        (unsigned)__float_as_int(v), (unsigned)__float_as_int(v), false, false);
    return __int_as_float((int)(hi ? r.x : r.y));
#else
    return __shfl_xor(v, 32);
#endif
}

template<int Q>
__device__ __forceinline__ float lane_xor(float v, bool hi) {
    if constexpr (Q == 0) return xor1p(v);
    else if constexpr (Q == 1) return xor2p(v);
    else if constexpr (Q == 2) return xor4p(v);
    else if constexpr (Q == 3) return xor8p(v);
    else if constexpr (Q == 4) return xor16p(v, hi);
    else return xor32p(v, hi);
}

// ---- packed complex gate core (verified r5/r6, absmax 0) ----
// cgate<false>(v,w) = A v + B w           (row select-bit = 0)
// cgate<true >(v,w) = conj(A) v - conj(B) w  (row select-bit = 1)
template<bool NEG>
__device__ __forceinline__ float2 cgate(const float2 ar2, const float2 ai2,
                                        const float2 br2, const float2 bi2,
                                        const float2 v, const float2 w) {
    float2 acc;
    asm("v_pk_mul_f32 %0, %1, %2" : "=v"(acc) : "v"(ar2), "v"(v));
    if constexpr (!NEG) {
        asm("v_pk_fma_f32 %0, %1, %2, %0 op_sel:[0,1,0] op_sel_hi:[1,0,1] neg_lo:[0,1,0]"
            : "+v"(acc) : "v"(ai2), "v"(v));
        asm("v_pk_fma_f32 %0, %1, %2, %0" : "+v"(acc) : "v"(br2), "v"(w));
    } else {
        asm("v_pk_fma_f32 %0, %1, %2, %0 op_sel:[0,1,0] op_sel_hi:[1,0,1] neg_lo:[1,1,0] neg_hi:[1,0,0]"
            : "+v"(acc) : "v"(ai2), "v"(v));
        asm("v_pk_fma_f32 %0, %1, %2, %0 neg_lo:[1,0,0] neg_hi:[1,0,0]"
            : "+v"(acc) : "v"(br2), "v"(w));
    }
    asm("v_pk_fma_f32 %0, %1, %2, %0 op_sel:[0,1,0] op_sel_hi:[1,0,1] neg_lo:[0,1,0]"
        : "+v"(acc) : "v"(bi2), "v"(w));
    return acc;
}

template<int Q>
__device__ __forceinline__ void lane_gate(float2 (&st)[8], int lane,
                                          float ar, float ai, float br, float bi) {
    const bool hi = (lane & (1 << Q)) != 0;
    const float aiL = hi ? -ai : ai;
    const float brL = hi ? -br : br;
    const float2 ar2 = make_float2(ar, ar);
    const float2 ai2 = make_float2(aiL, aiL);
    const float2 br2 = make_float2(brL, brL);
    const float2 bi2 = make_float2(bi, bi);
    #pragma unroll
    for (int r = 0; r < 8; ++r) {
        float2 p;
        p.x = lane_xor<Q>(st[r].x, hi);
        p.y = lane_xor<Q>(st[r].y, hi);
        st[r] = cgate<false>(ar2, ai2, br2, bi2, st[r], p);
    }
}

template<int RB>
__device__ __forceinline__ void reg_gate(float2 (&st)[8],
                                         float ar, float ai, float br, float bi) {
    const float2 ar2 = make_float2(ar, ar);
    const float2 ai2 = make_float2(ai, ai);
    const float2 br2 = make_float2(br, br);
    const float2 bi2 = make_float2(bi, bi);
    #pragma unroll
    for (int r = 0; r < 8; ++r) {
        if ((r & RB) == 0) {
            const int r1 = r | RB;
            const float2 v0 = st[r], v1 = st[r1];
            st[r]  = cgate<false>(ar2, ai2, br2, bi2, v0, v1);
            st[r1] = cgate<true >(ar2, ai2, br2, bi2, v1, v0);
        }
    }
}

__global__ __launch_bounds__(128, 4) void cqv_kernel(
    const float* __restrict__ x,
    const float* __restrict__ theta,
    const float* __restrict__ alpha_raw,
    const float* __restrict__ beta_raw,
    const float* __restrict__ head_w,
    const float* __restrict__ head_b,
    const float* __restrict__ logit_scale,
    float* __restrict__ out,
    int batch)
{
    const int lane = threadIdx.x & 63;
    const int wv = threadIdx.x >> 6;           // qubit-9 bit of this wave
    const int s = blockIdx.x;                  // one sample per block (grid exact)

    // [buf][reg][wv][lane] ; + epilogue partials. 8KB + 8B.
    __shared__ float2 lds[2][8][2][64];
    __shared__ float pbuf[2];

    const int l5 = (lane >> 5) & 1;
    const int srcLane = lane ^ ((lane & 31) << 1);

    // ---- per-lane gate params: lane g holds gate g = layer*10 + qubit ----
    const int g = (lane < 30) ? lane : 0;
    const float alpha = log1pf(__expf(alpha_raw[g])) + 1e-6f;
    const float beta  = tanhf(beta_raw[g]);
    const float halfE = 0.5f * PI_F * (alpha * x[s * 49 + g] + beta);
    float cE, sE, cT, sT;
    __sincosf(halfE, &sE, &cE);
    __sincosf(0.5f * theta[g], &sT, &cT);

    // r8: gate matrix quadruple, computed ONCE per lane (bit-exact move of
    // the per-gate products before the broadcast).
    // U row0 = (A, B); row1 = (-conj(B), conj(A)) via cgate<NEG>.
    const float gAr = cT * cE;     // A.re
    const float gAi = -sT * sE;    // A.im
    const float gBr = -cT * sE;    // B.re
    const float gBi = -sT * cE;    // B.im
    const float gNr = -gBr;        // (-conj(B)).re = ct*se

    float2 st[8];

    // ---- layer 0 on |0..0>: product state, q9 factor chosen by wv ----
    {
        float u0r[10], u0i[10], u1r[10], u1i[10];
        #pragma unroll
        for (int q = 0; q < 10; ++q) {
            u0r[q] = rdlane(gAr, q);  u0i[q] = rdlane(gAi, q);   // A
            u1r[q] = rdlane(gNr, q);  u1i[q] = rdlane(gBi, q);   // -conj(B)
        }
        float plr = 1.f, pli = 0.f;                  // lane bits 0..5
        #pragma unroll
        for (int q = 0; q < 6; ++q) {
            const bool bq = (lane >> q) & 1;
            const float wr = bq ? u1r[q] : u0r[q];
            const float wi = bq ? u1i[q] : u0i[q];
            const float nr = plr * wr - pli * wi;
            const float ni = plr * wi + pli * wr;
            plr = nr; pli = ni;
        }
        const float w9r = wv ? u1r[9] : u0r[9], w9i = wv ? u1i[9] : u0i[9];
        float t67r[4], t67i[4], t89r[2], t89i[2];
        #pragma unroll
        for (int a = 0; a < 4; ++a) {
            const float w6r = (a & 1) ? u1r[6] : u0r[6], w6i = (a & 1) ? u1i[6] : u0i[6];
            const float w7r = (a & 2) ? u1r[7] : u0r[7], w7i = (a & 2) ? u1i[7] : u0i[7];
            t67r[a] = w6r * w7r - w6i * w7i;  t67i[a] = w6r * w7i + w6i * w7r;
        }
        #pragma unroll
        for (int k = 0; k < 2; ++k) {
            const float w8r = k ? u1r[8] : u0r[8], w8i = k ? u1i[8] : u0i[8];
            t89r[k] = w8r * w9r - w8i * w9i;  t89i[k] = w8r * w9i + w8i * w9r;
        }
        #pragma unroll
        for (int r = 0; r < 8; ++r) {
            const float ar = t67r[r & 3] * t89r[r >> 2] - t67i[r & 3] * t89i[r >> 2];
            const float ai = t67r[r & 3] * t89i[r >> 2] + t67i[r & 3] * t89r[r >> 2];
            st[r].x = ar * plr - ai * pli;
            st[r].y = ar * pli + ai * plr;
        }
    }

    // ---- layer-0 CNOT chain: pure cross-wave permutation (buf 0) ----
    {
        #pragma unroll
        for (int r = 0; r < 8; ++r) lds[0][r][wv][lane] = st[r];
        __syncthreads();
        #pragma unroll
        for (int r = 0; r < 8; ++r) {
            const int sReg = (r ^ ((r & 3) << 1)) ^ l5;
            const int k9 = wv ^ (r >> 2);
            st[r] = lds[0][sReg][k9][srcLane];
        }
    }

#define GATE_PARAMS(BASE, Q) \
        const float ar = rdlane(gAr, (BASE) + (Q)), ai = rdlane(gAi, (BASE) + (Q)); \
        const float br = rdlane(gBr, (BASE) + (Q)), bi = rdlane(gBi, (BASE) + (Q));
#define APPLY_LANE_GATE(BASE, Q) { GATE_PARAMS(BASE, Q) \
        lane_gate<Q>(st, lane, ar, ai, br, bi); }
#define APPLY_REG_GATE(BASE, Q, RB) { GATE_PARAMS(BASE, Q) \
        reg_gate<RB>(st, ar, ai, br, bi); }
#define APPLY_Q0_Q8(BASE) \
        APPLY_LANE_GATE(BASE, 0) APPLY_LANE_GATE(BASE, 1) APPLY_LANE_GATE(BASE, 2) \
        APPLY_LANE_GATE(BASE, 3) APPLY_LANE_GATE(BASE, 4) APPLY_LANE_GATE(BASE, 5) \
        APPLY_REG_GATE(BASE, 6, 1) APPLY_REG_GATE(BASE, 7, 2) APPLY_REG_GATE(BASE, 8, 4)

    // ---- layer 1: q0..q8 in-wave; q9 fused into CNOT exchange (buf 1) ----
    {
        APPLY_Q0_Q8(10)
        GATE_PARAMS(10, 9)
        const float2 ar2 = make_float2(ar, ar), ai2 = make_float2(ai, ai);
        const float2 br2 = make_float2(br, br), bi2 = make_float2(bi, bi);
        #pragma unroll
        for (int r = 0; r < 8; ++r) lds[1][r][wv][lane] = st[r];
        __syncthreads();
        #pragma unroll
        for (int r = 0; r < 8; ++r) {
            const int sReg = (r ^ ((r & 3) << 1)) ^ l5;
            const int k9 = wv ^ (r >> 2);
            const float2 v = lds[1][sReg][k9][srcLane];
            const float2 w = lds[1][sReg][k9 ^ 1][srcLane];
            if (k9 == 0) st[r] = cgate<false>(ar2, ai2, br2, bi2, v, w);
            else         st[r] = cgate<true >(ar2, ai2, br2, bi2, v, w);
        }
    }

    // ---- layer 2: q0..q8 in-wave; q9 = same-address pair swap (buf 0,
    // safe: L1's barrier orders all L0 reads before this write). The final
    // CNOT chain is absorbed into the head weights below. ----
    {
        APPLY_Q0_Q8(20)
        GATE_PARAMS(20, 9)
        const float2 ar2 = make_float2(ar, ar), ai2 = make_float2(ai, ai);
        const float2 br2 = make_float2(br, br), bi2 = make_float2(bi, bi);
        #pragma unroll
        for (int r = 0; r < 8; ++r) lds[0][r][wv][lane] = st[r];
        __syncthreads();
        #pragma unroll
        for (int r = 0; r < 8; ++r) {
            const float2 w = lds[0][r][wv ^ 1][lane];   // partner amplitude
            if (wv == 0) st[r] = cgate<false>(ar2, ai2, br2, bi2, st[r], w);
            else         st[r] = cgate<true >(ar2, ai2, br2, bi2, st[r], w);
        }
    }
#undef GATE_PARAMS
#undef APPLY_LANE_GATE
#undef APPLY_REG_GATE
#undef APPLY_Q0_Q8

    // ---- epilogue with permuted weights W'(k) = sum_q w_q*(1-2*prefix_q(k)),
    // prefix_q(k) = k_0^..^k_q  (absorbs the final CNOT chain). ----
    float w[10];
    #pragma unroll
    for (int q = 0; q < 10; ++q) w[q] = head_w[q];
    // lane part: prefixes of bits 0..5, and lane parity sign
    float wlane = 0.f;
    {
        int pref = 0;
        #pragma unroll
        for (int q = 0; q < 6; ++q) {
            pref ^= (lane >> q) & 1;
            wlane += pref ? -w[q] : w[q];
        }
    }
    const float sPL = ((__builtin_popcount(lane & 63) & 1) ? -1.f : 1.f);
    // reg+wv part: wreg'(r) = w6*s(r0) + w7*s(r0^r1) + w8*s(pr2) + w9*s(pr2^wv)
    float acc = 0.f, psum = 0.f;
    #pragma unroll
    for (int r = 0; r < 8; ++r) {
        const float pw = st[r].x * st[r].x + st[r].y * st[r].y;
        const int p0 = r & 1, p1 = p0 ^ ((r >> 1) & 1), p2 = p1 ^ ((r >> 2) & 1);
        const float wr = (p0 ? -w[6] : w[6]) + (p1 ? -w[7] : w[7])
                       + (p2 ? -w[8] : w[8]) + ((p2 ^ wv) ? -w[9] : w[9]);
        psum += pw;
        acc = fmaf(wr, pw, acc);
    }
    float partial = fmaf(wlane, psum, sPL * acc);
    #pragma unroll
    for (int off = 32; off >= 1; off >>= 1) partial += __shfl_xor(partial, off);

    if (lane == 0) pbuf[wv] = partial;
    __syncthreads();
    if (threadIdx.x == 0) {
        const float scale = fminf(fmaxf(logit_scale[0], 0.5f), 80.f);
        const float raw = pbuf[0] + pbuf[1] + head_b[0];
        out[s] = fminf(fmaxf(scale * raw, -30.f), 30.f);
    }
}

extern "C" void kernel_launch(void* const* d_in, const int* in_sizes, int n_in,
                              void* d_out, int out_size, void* d_ws, size_t ws_size,
                              hipStream_t stream) {
    const int B = in_sizes[0] / 49;          // BATCH = 2048
    dim3 block(128);                         // 2 waves = 1 sample
    dim3 grid(B);
    cqv_kernel<<<grid, block, 0, stream>>>(
        (const float*)d_in[0], (const float*)d_in[1], (const float*)d_in[2],
        (const float*)d_in[3], (const float*)d_in[4], (const float*)d_in[5],
        (const float*)d_in[6], (float*)d_out, B);
}

// Round 4
// 80.795 us; speedup vs baseline: 1.0022x; 1.0022x over previous
//
#include <hip/hip_runtime.h>
#include <math.h>

// TWO waves per sample, ONE sample per block (block=128). Amplitude i:
//   bits 0..5 -> lane, bits 6..8 -> register (8 float2/lane), bit 9 -> wave.
// Layers: fused U_q = RX(theta)*RY(enc); CNOT chain = permutation
// src(j) = j ^ ((j&511)<<1). Layer-0 acts on |0..0> -> product state.
// Layer-2's FINAL CNOT chain is absorbed into the head weights via
// prefix-XOR signs (W'(k) = sum_q w_q * (1-2*(k_0^..^k_q))).
//
// r10: EXACT restore of the verified r8 kernel (passed, absmax 0.0,
// dur_us 80.97).
// Post-mortem r7/r9: both rewrites failed with absmax == 5.566406e-02
// == max|reference| -> output buffer effectively unwritten (harness
// memsets out to 0); wholesale runtime failure, not math error. Retired.
// Profile evidence (r8 run): top-5 dispatches are ALL harness
// fillBufferAligned, 256 MiB @ 6.7-6.8 TB/s = 84-85% HBM peak (the
// achievable ceiling); cqv_kernel absent (<39us, bounded ~1-2us by issue
// count). dur_us ~ 81 = two poison fills + kernel. The bench floor is the
// harness re-poison at the HBM roofline; kernel deltas are unmeasurable.

#define PI_F 3.14159265358979323846f

typedef unsigned v2u __attribute__((ext_vector_type(2)));

#if defined(__has_builtin)
#if __has_builtin(__builtin_amdgcn_permlane16_swap)
#define HAVE_PL16 1
#endif
#if __has_builtin(__builtin_amdgcn_permlane32_swap)
#define HAVE_PL32 1
#endif
#endif

__device__ __forceinline__ float rdlane(float v, int l) {
    return __int_as_float(__builtin_amdgcn_readlane(__float_as_int(v), l));
}

// ---- VALU-pipe lane^mask partner fetch (verified r4-r8, absmax 0) ----
__device__ __forceinline__ float xor1p(float v) {
    return __int_as_float(__builtin_amdgcn_update_dpp(
        0, __float_as_int(v), 0xB1, 0xF, 0xF, true));
}
__device__ __forceinline__ float xor2p(float v) {
    return __int_as_float(__builtin_amdgcn_update_dpp(
        0, __float_as_int(v), 0x4E, 0xF, 0xF, true));
}
__device__ __forceinline__ float xor4p(float v) {   // xor7 ∘ xor3 = xor4
    int t = __builtin_amdgcn_update_dpp(0, __float_as_int(v), 0x1B, 0xF, 0xF, true);
    t = __builtin_amdgcn_update_dpp(0, t, 0x141, 0xF, 0xF, true);
    return __int_as_float(t);
}
__device__ __forceinline__ float xor8p(float v) {   // row_ror:8
    return __int_as_float(__builtin_amdgcn_update_dpp(
        0, __float_as_int(v), 0x128, 0xF, 0xF, true));
}
__device__ __forceinline__ float xor16p(float v, bool hi) {
#ifdef HAVE_PL16
    v2u r = __builtin_amdgcn_permlane16_swap(
        (unsigned)__float_as_int(v), (unsigned)__float_as_int(v), false, false);
    return __int_as_float((int)(hi ? r.x : r.y));
#else
    return __shfl_xor(v, 16);
#endif
}
__device__ __forceinline__ float xor32p(float v, bool hi) {
#ifdef HAVE_PL32
    v2u r = __builtin_amdgcn_permlane32_swap(
        (unsigned)__float_as_int(v), (unsigned)__float_as_int(v), false, false);
    return __int_as_float((int)(hi ? r.x : r.y));
#else
    return __shfl_xor(v, 32);
#endif
}

template<int Q>
__device__ __forceinline__ float lane_xor(float v, bool hi) {
    if constexpr (Q == 0) return xor1p(v);
    else if constexpr (Q == 1) return xor2p(v);
    else if constexpr (Q == 2) return xor4p(v);
    else if constexpr (Q == 3) return xor8p(v);
    else if constexpr (Q == 4) return xor16p(v, hi);
    else return xor32p(v, hi);
}

// ---- packed complex gate core (verified r5-r8, absmax 0) ----
// cgate<false>(v,w) = A v + B w           (row select-bit = 0)
// cgate<true >(v,w) = conj(A) v - conj(B) w  (row select-bit = 1)
template<bool NEG>
__device__ __forceinline__ float2 cgate(const float2 ar2, const float2 ai2,
                                        const float2 br2, const float2 bi2,
                                        const float2 v, const float2 w) {
    float2 acc;
    asm("v_pk_mul_f32 %0, %1, %2" : "=v"(acc) : "v"(ar2), "v"(v));
    if constexpr (!NEG) {
        asm("v_pk_fma_f32 %0, %1, %2, %0 op_sel:[0,1,0] op_sel_hi:[1,0,1] neg_lo:[0,1,0]"
            : "+v"(acc) : "v"(ai2), "v"(v));
        asm("v_pk_fma_f32 %0, %1, %2, %0" : "+v"(acc) : "v"(br2), "v"(w));
    } else {
        asm("v_pk_fma_f32 %0, %1, %2, %0 op_sel:[0,1,0] op_sel_hi:[1,0,1] neg_lo:[1,1,0] neg_hi:[1,0,0]"
            : "+v"(acc) : "v"(ai2), "v"(v));
        asm("v_pk_fma_f32 %0, %1, %2, %0 neg_lo:[1,0,0] neg_hi:[1,0,0]"
            : "+v"(acc) : "v"(br2), "v"(w));
    }
    asm("v_pk_fma_f32 %0, %1, %2, %0 op_sel:[0,1,0] op_sel_hi:[1,0,1] neg_lo:[0,1,0]"
        : "+v"(acc) : "v"(bi2), "v"(w));
    return acc;
}

template<int Q>
__device__ __forceinline__ void lane_gate(float2 (&st)[8], int lane,
                                          float ar, float ai, float br, float bi) {
    const bool hi = (lane & (1 << Q)) != 0;
    const float aiL = hi ? -ai : ai;
    const float brL = hi ? -br : br;
    const float2 ar2 = make_float2(ar, ar);
    const float2 ai2 = make_float2(aiL, aiL);
    const float2 br2 = make_float2(brL, brL);
    const float2 bi2 = make_float2(bi, bi);
    #pragma unroll
    for (int r = 0; r < 8; ++r) {
        float2 p;
        p.x = lane_xor<Q>(st[r].x, hi);
        p.y = lane_xor<Q>(st[r].y, hi);
        st[r] = cgate<false>(ar2, ai2, br2, bi2, st[r], p);
    }
}

template<int RB>
__device__ __forceinline__ void reg_gate(float2 (&st)[8],
                                         float ar, float ai, float br, float bi) {
    const float2 ar2 = make_float2(ar, ar);
    const float2 ai2 = make_float2(ai, ai);
    const float2 br2 = make_float2(br, br);
    const float2 bi2 = make_float2(bi, bi);
    #pragma unroll
    for (int r = 0; r < 8; ++r) {
        if ((r & RB) == 0) {
            const int r1 = r | RB;
            const float2 v0 = st[r], v1 = st[r1];
            st[r]  = cgate<false>(ar2, ai2, br2, bi2, v0, v1);
            st[r1] = cgate<true >(ar2, ai2, br2, bi2, v1, v0);
        }
    }
}

__global__ __launch_bounds__(128, 4) void cqv_kernel(
    const float* __restrict__ x,
    const float* __restrict__ theta,
    const float* __restrict__ alpha_raw,
    const float* __restrict__ beta_raw,
    const float* __restrict__ head_w,
    const float* __restrict__ head_b,
    const float* __restrict__ logit_scale,
    float* __restrict__ out,
    int batch)
{
    const int lane = threadIdx.x & 63;
    const int wv = threadIdx.x >> 6;           // qubit-9 bit of this wave
    const int s = blockIdx.x;                  // one sample per block (grid exact)

    // [buf][reg][wv][lane] ; + epilogue partials. 8KB + 8B.
    __shared__ float2 lds[2][8][2][64];
    __shared__ float pbuf[2];

    const int l5 = (lane >> 5) & 1;
    const int srcLane = lane ^ ((lane & 31) << 1);

    // ---- per-lane gate params: lane g holds gate g = layer*10 + qubit ----
    const int g = (lane < 30) ? lane : 0;
    const float alpha = log1pf(__expf(alpha_raw[g])) + 1e-6f;
    const float beta  = tanhf(beta_raw[g]);
    const float halfE = 0.5f * PI_F * (alpha * x[s * 49 + g] + beta);
    float cE, sE, cT, sT;
    __sincosf(halfE, &sE, &cE);
    __sincosf(0.5f * theta[g], &sT, &cT);

    // Gate matrix quadruple, computed ONCE per lane (bit-exact move of the
    // per-gate products before the broadcast; verified r8).
    // U row0 = (A, B); row1 = (-conj(B), conj(A)) via cgate<NEG>.
    const float gAr = cT * cE;     // A.re
    const float gAi = -sT * sE;    // A.im
    const float gBr = -cT * sE;    // B.re
    const float gBi = -sT * cE;    // B.im
    const float gNr = -gBr;        // (-conj(B)).re = ct*se

    float2 st[8];

    // ---- layer 0 on |0..0>: product state, q9 factor chosen by wv ----
    {
        float u0r[10], u0i[10], u1r[10], u1i[10];
        #pragma unroll
        for (int q = 0; q < 10; ++q) {
            u0r[q] = rdlane(gAr, q);  u0i[q] = rdlane(gAi, q);   // A
            u1r[q] = rdlane(gNr, q);  u1i[q] = rdlane(gBi, q);   // -conj(B)
        }
        float plr = 1.f, pli = 0.f;                  // lane bits 0..5
        #pragma unroll
        for (int q = 0; q < 6; ++q) {
            const bool bq = (lane >> q) & 1;
            const float wr = bq ? u1r[q] : u0r[q];
            const float wi = bq ? u1i[q] : u0i[q];
            const float nr = plr * wr - pli * wi;
            const float ni = plr * wi + pli * wr;
            plr = nr; pli = ni;
        }
        const float w9r = wv ? u1r[9] : u0r[9], w9i = wv ? u1i[9] : u0i[9];
        float t67r[4], t67i[4], t89r[2], t89i[2];
        #pragma unroll
        for (int a = 0; a < 4; ++a) {
            const float w6r = (a & 1) ? u1r[6] : u0r[6], w6i = (a & 1) ? u1i[6] : u0i[6];
            const float w7r = (a & 2) ? u1r[7] : u0r[7], w7i = (a & 2) ? u1i[7] : u0i[7];
            t67r[a] = w6r * w7r - w6i * w7i;  t67i[a] = w6r * w7i + w6i * w7r;
        }
        #pragma unroll
        for (int k = 0; k < 2; ++k) {
            const float w8r = k ? u1r[8] : u0r[8], w8i = k ? u1i[8] : u0i[8];
            t89r[k] = w8r * w9r - w8i * w9i;  t89i[k] = w8r * w9i + w8i * w9r;
        }
        #pragma unroll
        for (int r = 0; r < 8; ++r) {
            const float ar = t67r[r & 3] * t89r[r >> 2] - t67i[r & 3] * t89i[r >> 2];
            const float ai = t67r[r & 3] * t89i[r >> 2] + t67i[r & 3] * t89r[r >> 2];
            st[r].x = ar * plr - ai * pli;
            st[r].y = ar * pli + ai * plr;
        }
    }

    // ---- layer-0 CNOT chain: pure cross-wave permutation (buf 0) ----
    {
        #pragma unroll
        for (int r = 0; r < 8; ++r) lds[0][r][wv][lane] = st[r];
        __syncthreads();
        #pragma unroll
        for (int r = 0; r < 8; ++r) {
            const int sReg = (r ^ ((r & 3) << 1)) ^ l5;
            const int k9 = wv ^ (r >> 2);
            st[r] = lds[0][sReg][k9][srcLane];
        }
    }

#define GATE_PARAMS(BASE, Q) \
        const float ar = rdlane(gAr, (BASE) + (Q)), ai = rdlane(gAi, (BASE) + (Q)); \
        const float br = rdlane(gBr, (BASE) + (Q)), bi = rdlane(gBi, (BASE) + (Q));
#define APPLY_LANE_GATE(BASE, Q) { GATE_PARAMS(BASE, Q) \
        lane_gate<Q>(st, lane, ar, ai, br, bi); }
#define APPLY_REG_GATE(BASE, Q, RB) { GATE_PARAMS(BASE, Q) \
        reg_gate<RB>(st, ar, ai, br, bi); }
#define APPLY_Q0_Q8(BASE) \
        APPLY_LANE_GATE(BASE, 0) APPLY_LANE_GATE(BASE, 1) APPLY_LANE_GATE(BASE, 2) \
        APPLY_LANE_GATE(BASE, 3) APPLY_LANE_GATE(BASE, 4) APPLY_LANE_GATE(BASE, 5) \
        APPLY_REG_GATE(BASE, 6, 1) APPLY_REG_GATE(BASE, 7, 2) APPLY_REG_GATE(BASE, 8, 4)

    // ---- layer 1: q0..q8 in-wave; q9 fused into CNOT exchange (buf 1) ----
    {
        APPLY_Q0_Q8(10)
        GATE_PARAMS(10, 9)
        const float2 ar2 = make_float2(ar, ar), ai2 = make_float2(ai, ai);
        const float2 br2 = make_float2(br, br), bi2 = make_float2(bi, bi);
        #pragma unroll
        for (int r = 0; r < 8; ++r) lds[1][r][wv][lane] = st[r];
        __syncthreads();
        #pragma unroll
        for (int r = 0; r < 8; ++r) {
            const int sReg = (r ^ ((r & 3) << 1)) ^ l5;
            const int k9 = wv ^ (r >> 2);
            const float2 v = lds[1][sReg][k9][srcLane];
            const float2 w = lds[1][sReg][k9 ^ 1][srcLane];
            if (k9 == 0) st[r] = cgate<false>(ar2, ai2, br2, bi2, v, w);
            else         st[r] = cgate<true >(ar2, ai2, br2, bi2, v, w);
        }
    }

    // ---- layer 2: q0..q8 in-wave; q9 = same-address pair swap (buf 0,
    // safe: L1's barrier orders all L0 reads before this write). The final
    // CNOT chain is absorbed into the head weights below. ----
    {
        APPLY_Q0_Q8(20)
        GATE_PARAMS(20, 9)
        const float2 ar2 = make_float2(ar, ar), ai2 = make_float2(ai, ai);
        const float2 br2 = make_float2(br, br), bi2 = make_float2(bi, bi);
        #pragma unroll
        for (int r = 0; r < 8; ++r) lds[0][r][wv][lane] = st[r];
        __syncthreads();
        #pragma unroll
        for (int r = 0; r < 8; ++r) {
            const float2 w = lds[0][r][wv ^ 1][lane];   // partner amplitude
            if (wv == 0) st[r] = cgate<false>(ar2, ai2, br2, bi2, st[r], w);
            else         st[r] = cgate<true >(ar2, ai2, br2, bi2, st[r], w);
        }
    }
#undef GATE_PARAMS
#undef APPLY_LANE_GATE
#undef APPLY_REG_GATE
#undef APPLY_Q0_Q8

    // ---- epilogue with permuted weights W'(k) = sum_q w_q*(1-2*prefix_q(k)),
    // prefix_q(k) = k_0^..^k_q  (absorbs the final CNOT chain). ----
    float w[10];
    #pragma unroll
    for (int q = 0; q < 10; ++q) w[q] = head_w[q];
    // lane part: prefixes of bits 0..5, and lane parity sign
    float wlane = 0.f;
    {
        int pref = 0;
        #pragma unroll
        for (int q = 0; q < 6; ++q) {
            pref ^= (lane >> q) & 1;
            wlane += pref ? -w[q] : w[q];
        }
    }
    const float sPL = ((__builtin_popcount(lane & 63) & 1) ? -1.f : 1.f);
    // reg+wv part: wreg'(r) = w6*s(r0) + w7*s(r0^r1) + w8*s(pr2) + w9*s(pr2^wv)
    float acc = 0.f, psum = 0.f;
    #pragma unroll
    for (int r = 0; r < 8; ++r) {
        const float pw = st[r].x * st[r].x + st[r].y * st[r].y;
        const int p0 = r & 1, p1 = p0 ^ ((r >> 1) & 1), p2 = p1 ^ ((r >> 2) & 1);
        const float wr = (p0 ? -w[6] : w[6]) + (p1 ? -w[7] : w[7])
                       + (p2 ? -w[8] : w[8]) + ((p2 ^ wv) ? -w[9] : w[9]);
        psum += pw;
        acc = fmaf(wr, pw, acc);
    }
    float partial = fmaf(wlane, psum, sPL * acc);
    #pragma unroll
    for (int off = 32; off >= 1; off >>= 1) partial += __shfl_xor(partial, off);

    if (lane == 0) pbuf[wv] = partial;
    __syncthreads();
    if (threadIdx.x == 0) {
        const float scale = fminf(fmaxf(logit_scale[0], 0.5f), 80.f);
        const float raw = pbuf[0] + pbuf[1] + head_b[0];
        out[s] = fminf(fmaxf(scale * raw, -30.f), 30.f);
    }
}

extern "C" void kernel_launch(void* const* d_in, const int* in_sizes, int n_in,
                              void* d_out, int out_size, void* d_ws, size_t ws_size,
                              hipStream_t stream) {
    const int B = in_sizes[0] / 49;          // BATCH = 2048
    dim3 block(128);                         // 2 waves = 1 sample
    dim3 grid(B);
    cqv_kernel<<<grid, block, 0, stream>>>(
        (const float*)d_in[0], (const float*)d_in[1], (const float*)d_in[2],
        (const float*)d_in[3], (const float*)d_in[4], (const float*)d_in[5],
        (const float*)d_in[6], (float*)d_out, B);
}